// Round 4
// baseline (122.334 us; speedup 1.0000x reference)
//
#include <hip/hip_runtime.h>
#include <math.h>

// PointsGeneration: elementwise sigmoid + threshold-gated regression concat.
//
// R3: fused single-pass (every plane read exactly once) with NONTEMPORAL
// loads and stores. All 537 MB is stream-through with zero reuse; default
// write-allocate thrashes the 256 MiB L3 (268 MB in + 268 MB out). `nt`
// hints bypass cache allocation for pure streaming.
// Fix vs R2: __builtin_nontemporal_* requires a native clang vector type,
// not HIP_vector_type -> use ext_vector_type(4) float.

typedef float f32x4 __attribute__((ext_vector_type(4)));

static __device__ __forceinline__ float sigf(float x) {
    // Accurate fp32 sigmoid (expf, not __expf): threshold comparisons sit on
    // the sigmoid value; match the numpy fp32 reference to avoid mask flips.
    return 1.0f / (1.0f + expf(-x));
}

static __device__ __forceinline__ f32x4 ldnt4(const float* p) {
    return __builtin_nontemporal_load(reinterpret_cast<const f32x4*>(p));
}
static __device__ __forceinline__ void stnt4(float* p, f32x4 v) {
    __builtin_nontemporal_store(v, reinterpret_cast<f32x4*>(p));
}

__global__ __launch_bounds__(256) void points_gen_kernel(
    const float* __restrict__ p_text,
    const float* __restrict__ p_head,
    const float* __restrict__ p_tail,
    const float* __restrict__ p_bond,
    const float* __restrict__ p_rh,
    const float* __restrict__ p_rt,
    const float* __restrict__ p_rb,
    float* __restrict__ out)
{
    constexpr int N = 2048 * 2048;            // pixels per plane
    const int t = blockIdx.x * blockDim.x + threadIdx.x;  // 0 .. N/4-1
    const int i = t * 4;                      // pixel index (float4 granule)

    // ---- score planes: load, sigmoid, masks, store ----
    f32x4 st = ldnt4(p_text + i);
    f32x4 sh = ldnt4(p_head + i);
    f32x4 sl = ldnt4(p_tail + i);
    f32x4 sb = ldnt4(p_bond + i);

    f32x4 mh, ml, mb;
#pragma unroll
    for (int k = 0; k < 4; ++k) {
        st[k] = sigf(st[k]);
        sh[k] = sigf(sh[k]);
        sl[k] = sigf(sl[k]);
        sb[k] = sigf(sb[k]);
        const float mt = (st[k] > 0.45f) ? 1.0f : 0.0f;
        mh[k] = (sh[k] > 0.5f) ? mt : 0.0f;
        ml[k] = (sl[k] > 0.5f) ? mt : 0.0f;
        mb[k] = (sb[k] > 0.5f) ? 1.0f : 0.0f;
    }

    stnt4(out + 0 * N + i, st);
    stnt4(out + 1 * N + i, sh);
    stnt4(out + 2 * N + i, sl);
    stnt4(out + 3 * N + i, sb);

    // ---- gated regression planes ----
#pragma unroll
    for (int c = 0; c < 4; ++c) {
        f32x4 v = ldnt4(p_rh + c * N + i);
        v *= mh;
        stnt4(out + (4 + c) * N + i, v);
    }
#pragma unroll
    for (int c = 0; c < 4; ++c) {
        f32x4 v = ldnt4(p_rt + c * N + i);
        v *= ml;
        stnt4(out + (8 + c) * N + i, v);
    }
#pragma unroll
    for (int c = 0; c < 4; ++c) {
        f32x4 v = ldnt4(p_rb + c * N + i);
        v *= mb;
        stnt4(out + (12 + c) * N + i, v);
    }
}

extern "C" void kernel_launch(void* const* d_in, const int* in_sizes, int n_in,
                              void* d_out, int out_size, void* d_ws, size_t ws_size,
                              hipStream_t stream) {
    (void)in_sizes; (void)n_in; (void)out_size; (void)d_ws; (void)ws_size;

    const float* p_text = (const float*)d_in[0];
    const float* p_head = (const float*)d_in[1];
    const float* p_tail = (const float*)d_in[2];
    const float* p_bond = (const float*)d_in[3];
    const float* p_rh   = (const float*)d_in[4];
    const float* p_rt   = (const float*)d_in[5];
    const float* p_rb   = (const float*)d_in[6];
    float* out = (float*)d_out;

    constexpr int N = 2048 * 2048;
    constexpr int threads = 256;
    constexpr int n4 = N / 4;                 // one thread per 4 pixels
    constexpr int blocks = n4 / threads;      // 4096, exact

    points_gen_kernel<<<blocks, threads, 0, stream>>>(
        p_text, p_head, p_tail, p_bond, p_rh, p_rt, p_rb, out);
}

// Round 5
// 107.517 us; speedup vs baseline: 1.1378x; 1.1378x over previous
//
#include <hip/hip_runtime.h>
#include <math.h>

// PointsGeneration: elementwise sigmoid + threshold-gated regression concat.
//
// R4: long-run restructure. Each wave processes a 2048-pixel (8 KB) window
// per plane via 8 back-to-back dwordx4 loads/stores (lane-adjacent, 1 KB per
// instruction, j-offset 256 px), visiting streams SEQUENTIALLY instead of
// interleaving 1 KB granules across 23 streams. Tests the DRAM row-locality
// theory (R0/R1/R3 all 120 us regardless of structure => MC-level limiter).
// Masks held as per-thread 32-bit bitmasks so score regs retire early.

typedef float f32x4 __attribute__((ext_vector_type(4)));

static __device__ __forceinline__ float sigf(float x) {
    // Accurate fp32 sigmoid (expf, not __expf): threshold comparisons sit on
    // the sigmoid value; match the numpy fp32 reference to avoid mask flips.
    return 1.0f / (1.0f + expf(-x));
}

static __device__ __forceinline__ f32x4 ld4(const float* p) {
    return *reinterpret_cast<const f32x4*>(p);
}
static __device__ __forceinline__ void st4(float* p, f32x4 v) {
    *reinterpret_cast<f32x4*>(p) = v;
}

__global__ __launch_bounds__(256) void points_gen_kernel(
    const float* __restrict__ p_text,
    const float* __restrict__ p_head,
    const float* __restrict__ p_tail,
    const float* __restrict__ p_bond,
    const float* __restrict__ p_rh,
    const float* __restrict__ p_rt,
    const float* __restrict__ p_rb,
    float* __restrict__ out)
{
    constexpr int N = 2048 * 2048;   // pixels per plane
    constexpr int WPX = 2048;        // pixels per wave per plane (8 KB)
    const int lane = threadIdx.x & 63;
    const int wave = (blockIdx.x * blockDim.x + threadIdx.x) >> 6;  // 0..2047
    const int base = wave * WPX + lane * 4;   // + j*256 for j in 0..7

    // ---- phase 1: score planes (8 KB contiguous run per plane) ----
    f32x4 T[8], H[8], L[8], B[8];
#pragma unroll
    for (int j = 0; j < 8; ++j) T[j] = ld4(p_text + base + j * 256);
#pragma unroll
    for (int j = 0; j < 8; ++j) H[j] = ld4(p_head + base + j * 256);
#pragma unroll
    for (int j = 0; j < 8; ++j) L[j] = ld4(p_tail + base + j * 256);
#pragma unroll
    for (int j = 0; j < 8; ++j) B[j] = ld4(p_bond + base + j * 256);

    unsigned mt = 0, mh = 0, ml = 0, mb = 0;  // 32 pixel-bits each
#pragma unroll
    for (int j = 0; j < 8; ++j) {
#pragma unroll
        for (int k = 0; k < 4; ++k) {
            T[j][k] = sigf(T[j][k]);
            if (T[j][k] > 0.45f) mt |= 1u << (4 * j + k);
        }
    }
#pragma unroll
    for (int j = 0; j < 8; ++j) st4(out + 0 * N + base + j * 256, T[j]);

#pragma unroll
    for (int j = 0; j < 8; ++j) {
#pragma unroll
        for (int k = 0; k < 4; ++k) {
            H[j][k] = sigf(H[j][k]);
            if (H[j][k] > 0.5f) mh |= 1u << (4 * j + k);
        }
    }
#pragma unroll
    for (int j = 0; j < 8; ++j) st4(out + 1 * N + base + j * 256, H[j]);

#pragma unroll
    for (int j = 0; j < 8; ++j) {
#pragma unroll
        for (int k = 0; k < 4; ++k) {
            L[j][k] = sigf(L[j][k]);
            if (L[j][k] > 0.5f) ml |= 1u << (4 * j + k);
        }
    }
#pragma unroll
    for (int j = 0; j < 8; ++j) st4(out + 2 * N + base + j * 256, L[j]);

#pragma unroll
    for (int j = 0; j < 8; ++j) {
#pragma unroll
        for (int k = 0; k < 4; ++k) {
            B[j][k] = sigf(B[j][k]);
            if (B[j][k] > 0.5f) mb |= 1u << (4 * j + k);
        }
    }
#pragma unroll
    for (int j = 0; j < 8; ++j) st4(out + 3 * N + base + j * 256, B[j]);

    mh &= mt;   // head mask = text & head
    ml &= mt;   // tail mask = text & tail

    // ---- phase 2: gated regression planes, one 8 KB run per channel ----
#pragma unroll
    for (int c = 0; c < 4; ++c) {
        f32x4 v[8];
#pragma unroll
        for (int j = 0; j < 8; ++j) v[j] = ld4(p_rh + c * N + base + j * 256);
#pragma unroll
        for (int j = 0; j < 8; ++j)
#pragma unroll
            for (int k = 0; k < 4; ++k)
                v[j][k] = (mh >> (4 * j + k)) & 1u ? v[j][k] : 0.0f;
#pragma unroll
        for (int j = 0; j < 8; ++j) st4(out + (4 + c) * N + base + j * 256, v[j]);
    }
#pragma unroll
    for (int c = 0; c < 4; ++c) {
        f32x4 v[8];
#pragma unroll
        for (int j = 0; j < 8; ++j) v[j] = ld4(p_rt + c * N + base + j * 256);
#pragma unroll
        for (int j = 0; j < 8; ++j)
#pragma unroll
            for (int k = 0; k < 4; ++k)
                v[j][k] = (ml >> (4 * j + k)) & 1u ? v[j][k] : 0.0f;
#pragma unroll
        for (int j = 0; j < 8; ++j) st4(out + (8 + c) * N + base + j * 256, v[j]);
    }
#pragma unroll
    for (int c = 0; c < 4; ++c) {
        f32x4 v[8];
#pragma unroll
        for (int j = 0; j < 8; ++j) v[j] = ld4(p_rb + c * N + base + j * 256);
#pragma unroll
        for (int j = 0; j < 8; ++j)
#pragma unroll
            for (int k = 0; k < 4; ++k)
                v[j][k] = (mb >> (4 * j + k)) & 1u ? v[j][k] : 0.0f;
#pragma unroll
        for (int j = 0; j < 8; ++j) st4(out + (12 + c) * N + base + j * 256, v[j]);
    }
}

extern "C" void kernel_launch(void* const* d_in, const int* in_sizes, int n_in,
                              void* d_out, int out_size, void* d_ws, size_t ws_size,
                              hipStream_t stream) {
    (void)in_sizes; (void)n_in; (void)out_size; (void)d_ws; (void)ws_size;

    const float* p_text = (const float*)d_in[0];
    const float* p_head = (const float*)d_in[1];
    const float* p_tail = (const float*)d_in[2];
    const float* p_bond = (const float*)d_in[3];
    const float* p_rh   = (const float*)d_in[4];
    const float* p_rt   = (const float*)d_in[5];
    const float* p_rb   = (const float*)d_in[6];
    float* out = (float*)d_out;

    constexpr int N = 2048 * 2048;
    constexpr int WPX = 2048;                       // pixels per wave per plane
    constexpr int waves = N / WPX;                  // 2048
    constexpr int threads = 256;                    // 4 waves per block
    constexpr int blocks = waves * 64 / threads;    // 512

    points_gen_kernel<<<blocks, threads, 0, stream>>>(
        p_text, p_head, p_tail, p_bond, p_rh, p_rt, p_rb, out);
}